// Round 14
// baseline (1129.519 us; speedup 1.0000x reference)
//
#include <hip/hip_runtime.h>
#include <cstdint>
#include <cstddef>

#define NNODES 50000
#define NEDGES 800000
#define IN_DIM 232
#define EMB 300
#define HID 600
#define NLAYERS 5
#define BN_EPS 1e-5f

#define MPAD 50048        // 391 * 128
#define K0P 256           // IN_DIM 232 -> 256
#define K1P 320           // EMB 300 -> 320
#define K2P 608           // HID 600 -> 608
#define N0P 384           // EMB out tiles (3 x 128)
#define N1P 640           // HID out tiles (5 x 128)
#define MT_TILES 391      // MPAD / 128
#define CSTR 140          // epilogue LDS C-tile row stride (elems)
#define NBH 196           // ceil(NNODES/256) histogram blocks

typedef unsigned short ushort_t;
typedef __attribute__((ext_vector_type(8))) short bf16x8;
typedef __attribute__((ext_vector_type(4))) float f32x4;

__device__ __forceinline__ float b2f(ushort_t u) {
    unsigned int x = (unsigned int)u << 16;
    return __builtin_bit_cast(float, x);
}
__device__ __forceinline__ ushort_t f2b(float f) {
    unsigned int x = __builtin_bit_cast(unsigned int, f);
    unsigned int r = (x + 0x7fffu + ((x >> 16) & 1u)) >> 16;
    return (ushort_t)r;
}

__device__ __forceinline__ void gl_lds16(const void* gsrc, void* ldst) {
    __builtin_amdgcn_global_load_lds(
        (const __attribute__((address_space(1))) void*)gsrc,
        (__attribute__((address_space(3))) void*)ldst, 16, 0, 0);
}

// ---------------- edge-index dtype detection (int64 vs int32) ----------------
__global__ void detect_mode_kernel(const unsigned int* __restrict__ ei, int* __restrict__ mode) {
    if (threadIdx.x == 0 && blockIdx.x == 0) {
        int nz = 0;
        for (int i = 0; i < 256; ++i) nz += (ei[2 * i + 1] != 0u);
        *mode = (nz == 0) ? 1 : 0;
    }
}
__device__ __forceinline__ int load_edge(const int* ei, int mode, long long idx) {
    if (mode) return (int)((const long long*)ei)[idx];
    return ei[idx];
}

// ---------------- CSR build ----------------
__global__ void hist_kernel(const int* __restrict__ ei, const int* __restrict__ mode,
                            int* __restrict__ deg) {
    int i = blockIdx.x * blockDim.x + threadIdx.x;
    if (i >= NEDGES) return;
    int d = load_edge(ei, *mode, (long long)NEDGES + i);
    atomicAdd(&deg[d], 1);
}

__global__ void scan_block_sums(const int* __restrict__ deg, int* __restrict__ bsum, int n) {
    __shared__ int s[256];
    int t = threadIdx.x;
    int i = blockIdx.x * 256 + t;
    s[t] = (i < n) ? deg[i] : 0;
    __syncthreads();
    for (int off = 128; off > 0; off >>= 1) {
        if (t < off) s[t] += s[t + off];
        __syncthreads();
    }
    if (t == 0) bsum[blockIdx.x] = s[0];
}

__global__ void scan_bsums(int* __restrict__ bsum, int nb) {
    __shared__ int s[256];
    int t = threadIdx.x;
    int v = (t < nb) ? bsum[t] : 0;
    s[t] = v;
    __syncthreads();
    for (int off = 1; off < 256; off <<= 1) {
        int u = (t >= off) ? s[t - off] : 0;
        __syncthreads();
        s[t] += u;
        __syncthreads();
    }
    if (t < nb) bsum[t] = s[t] - v;  // exclusive
}

__global__ void scan_final(const int* __restrict__ deg, const int* __restrict__ bsum,
                           int* __restrict__ offs, int* __restrict__ cursor, int n) {
    __shared__ int s[256];
    int t = threadIdx.x;
    int i = blockIdx.x * 256 + t;
    int v = (i < n) ? deg[i] : 0;
    s[t] = v;
    __syncthreads();
    for (int off = 1; off < 256; off <<= 1) {
        int u = (t >= off) ? s[t - off] : 0;
        __syncthreads();
        s[t] += u;
        __syncthreads();
    }
    int excl = s[t] - v + bsum[blockIdx.x];
    if (i < n) {
        offs[i] = excl;
        cursor[i] = excl;
        if (i == n - 1) offs[n] = excl + v;
    }
}

__global__ void fill_csr(const int* __restrict__ ei, const int* __restrict__ mode,
                         int* __restrict__ cursor, int* __restrict__ csr) {
    int i = blockIdx.x * blockDim.x + threadIdx.x;
    if (i >= NEDGES) return;
    int m = *mode;
    int s = load_edge(ei, m, i);
    int d = load_edge(ei, m, (long long)NEDGES + i);
    int p = atomicAdd(&cursor[d], 1);
    csr[p] = s;
}

// ---------------- contention-free degree counting sort (for aggregate pairing) --------
// perm[] = node ids in ascending-degree order. Pairing equal-degree nodes kills the
// dual-chain imbalance. Per-node accumulation order is perm-independent -> output
// bit-identical regardless of within-bucket rank order.
__global__ __launch_bounds__(256) void deg_hist_lds(const int* __restrict__ offs,
                                                    int* __restrict__ bh) {
    __shared__ int lh[256];
    const int t = threadIdx.x, j = blockIdx.x;
    lh[t] = 0;
    __syncthreads();
    const int i = j * 256 + t;
    if (i < NNODES) {
        int d = offs[i + 1] - offs[i];
        if (d > 255) d = 255;
        atomicAdd(&lh[d], 1);   // LDS atomic, low contention
    }
    __syncthreads();
    bh[j * 256 + t] = lh[t];
}
// 1 block, 256 threads: bh[j][b] -> global base cursor for (block j, bucket b), in place.
__global__ __launch_bounds__(256) void deg_scan2(int* __restrict__ bh) {
    __shared__ int tot[256];
    const int t = threadIdx.x;  // bucket
    int running = 0;
    for (int j = 0; j < NBH; ++j) {
        int v = bh[j * 256 + t];
        bh[j * 256 + t] = running;   // within-bucket exclusive prefix
        running += v;
    }
    tot[t] = running;
    __syncthreads();
    // exclusive scan over bucket totals
    int v = tot[t];
    for (int off = 1; off < 256; off <<= 1) {
        int u = (t >= off) ? tot[t - off] : 0;
        __syncthreads();
        tot[t] += u;
        __syncthreads();
    }
    const int base = tot[t] - v;
    for (int j = 0; j < NBH; ++j) bh[j * 256 + t] += base;
}
__global__ __launch_bounds__(256) void deg_scatter_lds(const int* __restrict__ offs,
                                                       const int* __restrict__ bh,
                                                       int* __restrict__ perm) {
    __shared__ int cur[256];
    const int t = threadIdx.x, j = blockIdx.x;
    cur[t] = bh[j * 256 + t];
    __syncthreads();
    const int i = j * 256 + t;
    if (i < NNODES) {
        int d = offs[i + 1] - offs[i];
        if (d > 255) d = 255;
        int pos = atomicAdd(&cur[d], 1);  // LDS atomic
        perm[pos] = i;
    }
}

// ---------------- conversions ----------------
// x [50000][232] f32 -> xb [MPAD][256] bf16, vectorized (232 = 29*8 exactly).
__global__ __launch_bounds__(256) void cast_x_kernel(const float* __restrict__ x,
                                                     ushort_t* __restrict__ o) {
    int idx = blockIdx.x * 256 + threadIdx.x;
    if (idx >= NNODES * 32) return;
    int row = idx >> 5, g = idx & 31;
    ushort_t* dst = o + (size_t)row * K0P + g * 8;
    if (g < 29) {
        const float* src = x + (size_t)row * IN_DIM + g * 8;
        float4 a = *(const float4*)src;
        float4 b = *(const float4*)(src + 4);
        ushort_t tmp[8] = {f2b(a.x), f2b(a.y), f2b(a.z), f2b(a.w),
                           f2b(b.x), f2b(b.y), f2b(b.z), f2b(b.w)};
        *(uint4*)dst = *(const uint4*)tmp;
    } else {
        uint4 zz = {0, 0, 0, 0};
        *(uint4*)dst = zz;
    }
}
__global__ void conv_lin_kernel(const float* __restrict__ w, ushort_t* __restrict__ o) {
    int idx = blockIdx.x * 256 + threadIdx.x;
    if (idx >= N0P * K0P) return;
    int n = idx >> 8, k = idx & 255;
    float v = (n < EMB && k < IN_DIM) ? w[(size_t)k * EMB + n] : 0.f;
    o[idx] = f2b(v);
}
__global__ void conv_w1_kernel(const float* __restrict__ w, ushort_t* __restrict__ o) {
    int idx = blockIdx.x * 256 + threadIdx.x;
    if (idx >= NLAYERS * N1P * K1P) return;
    int l = idx / (N1P * K1P);
    int r = idx - l * (N1P * K1P);
    int n = r / K1P, k = r - n * K1P;
    float v = (n < HID && k < EMB) ? w[((size_t)l * EMB + k) * HID + n] : 0.f;
    o[idx] = f2b(v);
}
__global__ void conv_w2_kernel(const float* __restrict__ w, ushort_t* __restrict__ o) {
    int idx = blockIdx.x * 256 + threadIdx.x;
    if (idx >= NLAYERS * N0P * K2P) return;
    int l = idx / (N0P * K2P);
    int r = idx - l * (N0P * K2P);
    int n = r / K2P, k = r - n * K2P;
    float v = (n < EMB && k < HID) ? w[((size_t)l * HID + k) * EMB + n] : 0.f;
    o[idx] = f2b(v);
}

// ---------------- aggregation: degree-paired dual-chain + 4-deep unroll ----------
// agg[v] = h[v] + sum_{u in N_in(v)} h[u]; h/agg are [MPAD][320] bf16, pad cols zeroed.
__global__ __launch_bounds__(256) void aggregate_bf16(
    const ushort_t* __restrict__ h, ushort_t* __restrict__ agg,
    const int* __restrict__ offs, const int* __restrict__ csr,
    const int* __restrict__ perm) {
    const int w = blockIdx.x * 4 + (threadIdx.x >> 6);
    const int lane = threadIdx.x & 63;
    if (w * 2 >= NNODES) return;  // NNODES even
    const int wid0 = perm[w * 2], wid1 = perm[w * 2 + 1];
    const bool hasb = lane < 11;  // slots 64..74 (cols 256..299)
    float a0[4], a1[4] = {0.f, 0.f, 0.f, 0.f};
    float c0[4], c1[4] = {0.f, 0.f, 0.f, 0.f};
    {
        const ushort4* r0 = (const ushort4*)(h + (size_t)wid0 * K1P);
        const ushort4* r1 = (const ushort4*)(h + (size_t)wid1 * K1P);
        ushort4 v0 = r0[lane], v1 = r1[lane];
        a0[0] = b2f(v0.x); a0[1] = b2f(v0.y); a0[2] = b2f(v0.z); a0[3] = b2f(v0.w);
        c0[0] = b2f(v1.x); c0[1] = b2f(v1.y); c0[2] = b2f(v1.z); c0[3] = b2f(v1.w);
        if (hasb) {
            ushort4 w0 = r0[64 + lane], w1 = r1[64 + lane];
            a1[0] = b2f(w0.x); a1[1] = b2f(w0.y); a1[2] = b2f(w0.z); a1[3] = b2f(w0.w);
            c1[0] = b2f(w1.x); c1[1] = b2f(w1.y); c1[2] = b2f(w1.z); c1[3] = b2f(w1.w);
        }
    }
    int p0 = offs[wid0], e0 = offs[wid0 + 1];
    int p1 = offs[wid1], e1 = offs[wid1 + 1];

    // ---- 4-deep unrolled main loop (both chains have >= 4 edges left)
    while (p0 + 4 <= e0 && p1 + 4 <= e1) {
        int s0[4], s1[4];
#pragma unroll
        for (int u = 0; u < 4; ++u) { s0[u] = csr[p0 + u]; s1[u] = csr[p1 + u]; }
        ushort4 x0[4], x1[4], y0[4], y1[4];
#pragma unroll
        for (int u = 0; u < 4; ++u) {
            const ushort4* r0 = (const ushort4*)(h + (size_t)s0[u] * K1P);
            const ushort4* r1 = (const ushort4*)(h + (size_t)s1[u] * K1P);
            x0[u] = r0[lane];
            x1[u] = r1[lane];
            if (hasb) { y0[u] = r0[64 + lane]; y1[u] = r1[64 + lane]; }
        }
#pragma unroll
        for (int u = 0; u < 4; ++u) {
            a0[0] += b2f(x0[u].x); a0[1] += b2f(x0[u].y); a0[2] += b2f(x0[u].z); a0[3] += b2f(x0[u].w);
            c0[0] += b2f(x1[u].x); c0[1] += b2f(x1[u].y); c0[2] += b2f(x1[u].z); c0[3] += b2f(x1[u].w);
            if (hasb) {
                a1[0] += b2f(y0[u].x); a1[1] += b2f(y0[u].y); a1[2] += b2f(y0[u].z); a1[3] += b2f(y0[u].w);
                c1[0] += b2f(y1[u].x); c1[1] += b2f(y1[u].y); c1[2] += b2f(y1[u].z); c1[3] += b2f(y1[u].w);
            }
        }
        p0 += 4; p1 += 4;
    }

    // ---- dual-chain single-step remainder
    while (p0 < e0 && p1 < e1) {
        const ushort4* r0 = (const ushort4*)(h + (size_t)csr[p0] * K1P); ++p0;
        const ushort4* r1 = (const ushort4*)(h + (size_t)csr[p1] * K1P); ++p1;
        ushort4 v0 = r0[lane];
        ushort4 v1 = r1[lane];
        a0[0] += b2f(v0.x); a0[1] += b2f(v0.y); a0[2] += b2f(v0.z); a0[3] += b2f(v0.w);
        c0[0] += b2f(v1.x); c0[1] += b2f(v1.y); c0[2] += b2f(v1.z); c0[3] += b2f(v1.w);
        if (hasb) {
            ushort4 w0 = r0[64 + lane];
            ushort4 w1 = r1[64 + lane];
            a1[0] += b2f(w0.x); a1[1] += b2f(w0.y); a1[2] += b2f(w0.z); a1[3] += b2f(w0.w);
            c1[0] += b2f(w1.x); c1[1] += b2f(w1.y); c1[2] += b2f(w1.z); c1[3] += b2f(w1.w);
        }
    }
    while (p0 < e0) {
        const ushort4* r0 = (const ushort4*)(h + (size_t)csr[p0] * K1P); ++p0;
        ushort4 v0 = r0[lane];
        a0[0] += b2f(v0.x); a0[1] += b2f(v0.y); a0[2] += b2f(v0.z); a0[3] += b2f(v0.w);
        if (hasb) {
            ushort4 w0 = r0[64 + lane];
            a1[0] += b2f(w0.x); a1[1] += b2f(w0.y); a1[2] += b2f(w0.z); a1[3] += b2f(w0.w);
        }
    }
    while (p1 < e1) {
        const ushort4* r1 = (const ushort4*)(h + (size_t)csr[p1] * K1P); ++p1;
        ushort4 v1 = r1[lane];
        c0[0] += b2f(v1.x); c0[1] += b2f(v1.y); c0[2] += b2f(v1.z); c0[3] += b2f(v1.w);
        if (hasb) {
            ushort4 w1 = r1[64 + lane];
            c1[0] += b2f(w1.x); c1[1] += b2f(w1.y); c1[2] += b2f(w1.z); c1[3] += b2f(w1.w);
        }
    }
    ushort4* o0 = (ushort4*)(agg + (size_t)wid0 * K1P);
    ushort4* o1 = (ushort4*)(agg + (size_t)wid1 * K1P);
    ushort4 ov;
    ov.x = f2b(a0[0]); ov.y = f2b(a0[1]); ov.z = f2b(a0[2]); ov.w = f2b(a0[3]);
    o0[lane] = ov;
    ov.x = f2b(c0[0]); ov.y = f2b(c0[1]); ov.z = f2b(c0[2]); ov.w = f2b(c0[3]);
    o1[lane] = ov;
    if (hasb) {
        ov.x = f2b(a1[0]); ov.y = f2b(a1[1]); ov.z = f2b(a1[2]); ov.w = f2b(a1[3]);
        o0[64 + lane] = ov;
        ov.x = f2b(c1[0]); ov.y = f2b(c1[1]); ov.z = f2b(c1[2]); ov.w = f2b(c1[3]);
        o1[64 + lane] = ov;
    }
    if (lane < 5) {  // zero K-pad cols 300..319
        ushort4 zz; zz.x = zz.y = zz.z = zz.w = 0;
        o0[75 + lane] = zz;
        o1[75 + lane] = zz;
    }
}

// ---------------- bf16 MFMA GEMM + XCD colocation (round-13 structure) ----------
// C = pro(A)[M,K] @ Bt[N,K]^T + bias.  128x128 tile, BK=32, 4 waves (2x2 of 64x64).
// Non-PRO: QUAD-buffered LDS, 2-ahead prefetch, one barrier per K-step.
// PRO (BN+ReLU fused on A): LDS double-buffer, 1-ahead.
// STATS: race-free per-(mt,wm) partial col sums (NO atomics), reduced by bn_reduce.
template <int PRO, int RELU, int STATS, int OUT_BF16>
__global__ __launch_bounds__(256) void gemm_mfma(
    const ushort_t* __restrict__ A, int lda,
    const ushort_t* __restrict__ Bt, int ldb,
    const float* __restrict__ bias,
    void* __restrict__ C, int ldc, int M, int N, int K,
    const float* __restrict__ pscale, const float* __restrict__ pshift, int Kreal,
    float* __restrict__ partials, int NB) {
    __shared__ ushort_t sh[PRO ? 17920 : 32768];
    __shared__ float psS[PRO ? 640 : 4];
    __shared__ float pfS[PRO ? 640 : 4];

    const int bid = blockIdx.x;
    const int xcd = bid & 7, slot = bid >> 3;
    const int mt = (slot / NB) * 8 + xcd;
    if (mt >= MT_TILES) return;
    const int nt = slot % NB;
    const int m0 = mt << 7, n0 = nt << 7;

    const int tid = threadIdx.x;
    const int wave = tid >> 6, lane = tid & 63;
    const int wm = wave >> 1, wn = wave & 1;
    const int NT = K >> 5;

    const int srow = lane >> 2;
    const int schunk = ((lane & 3) ^ ((lane >> 3) & 3)) << 3;
    const ushort_t* bP = Bt + (size_t)(n0 + (wave << 5) + srow) * ldb + schunk;
    const ushort_t* aPg = A + (size_t)(m0 + (wave << 5) + srow) * lda + schunk;
    const ushort_t* aPr = A + (size_t)(m0 + (wave << 5) + srow) * lda + ((lane & 3) << 3);
    const int a16 = lda << 4, b16 = ldb << 4;
    const int ldsW = wave << 10;

    const int fr = lane & 15, fq = lane >> 4;
    const int rdoff = (fq ^ ((fr >> 1) & 3)) << 3;

    f32x4 acc[4][4];
#pragma unroll
    for (int i = 0; i < 4; ++i)
#pragma unroll
        for (int j = 0; j < 4; ++j) acc[i][j] = {0.f, 0.f, 0.f, 0.f};

    if (PRO) {
        for (int i = tid; i < 640; i += 256) {
            psS[i] = (i < Kreal) ? pscale[i] : 0.f;
            pfS[i] = (i < Kreal) ? pshift[i] : 0.f;
        }
        __syncthreads();
    }

    if (!PRO) {
        const ushort_t* aN = aPg;
        const ushort_t* bN = bP;
        gl_lds16(aN, sh + ldsW);
        gl_lds16(aN + a16, sh + ldsW + 512);
        gl_lds16(bN, sh + 16384 + ldsW);
        gl_lds16(bN + b16, sh + 16384 + ldsW + 512);
        aN += 32; bN += 32;
        gl_lds16(aN, sh + 4096 + ldsW);
        gl_lds16(aN + a16, sh + 4096 + ldsW + 512);
        gl_lds16(bN, sh + 20480 + ldsW);
        gl_lds16(bN + b16, sh + 20480 + ldsW + 512);
        aN += 32; bN += 32;

        for (int t = 0; t < NT; ++t) {
            const int cb = t & 3;
            if (t + 2 < NT) {
                const int sb = (t + 2) & 3;
                gl_lds16(aN, sh + (sb << 12) + ldsW);
                gl_lds16(aN + a16, sh + (sb << 12) + ldsW + 512);
                gl_lds16(bN, sh + 16384 + (sb << 12) + ldsW);
                gl_lds16(bN + b16, sh + 16384 + (sb << 12) + ldsW + 512);
                aN += 32; bN += 32;
                asm volatile("s_waitcnt vmcnt(8)" ::: "memory");
            } else if (t + 1 < NT) {
                asm volatile("s_waitcnt vmcnt(4)" ::: "memory");
            } else {
                asm volatile("s_waitcnt vmcnt(0)" ::: "memory");
            }
            __builtin_amdgcn_s_barrier();
            __builtin_amdgcn_sched_barrier(0);

            const ushort_t* ASc = sh + (cb << 12);
            const ushort_t* BSc = sh + 16384 + (cb << 12);
            bf16x8 af[4], bf[4];
#pragma unroll
            for (int mi = 0; mi < 4; ++mi)
                af[mi] = *(const bf16x8*)&ASc[((wm << 6) + (mi << 4) + fr) * 32 + rdoff];
#pragma unroll
            for (int nj = 0; nj < 4; ++nj)
                bf[nj] = *(const bf16x8*)&BSc[((wn << 6) + (nj << 4) + fr) * 32 + rdoff];
#pragma unroll
            for (int mi = 0; mi < 4; ++mi)
#pragma unroll
                for (int nj = 0; nj < 4; ++nj)
                    acc[mi][nj] = __builtin_amdgcn_mfma_f32_16x16x32_bf16(af[mi], bf[nj], acc[mi][nj], 0, 0, 0);

            __builtin_amdgcn_sched_barrier(0);
        }
    } else {
        ushort_t* const AS0 = sh;
        ushort_t* const AS1 = sh + 4096;
        ushort_t* const BS0 = sh + 8192;
        ushort_t* const BS1 = sh + 12288;
        uint4 ar0, ar1;
        const ushort_t* aNext;
        const ushort_t* bNext = bP + 32;
        ar0 = *(const uint4*)aPr;
        ar1 = *(const uint4*)(aPr + a16);
        gl_lds16(bP, BS0 + ldsW);
        gl_lds16(bP + b16, BS0 + ldsW + 512);
        aNext = aPr + 32;

        int cur = 0;
        for (int t = 0; t < NT; ++t) {
            ushort_t* const ASc = cur ? AS1 : AS0;
            ushort_t* const BSn = cur ? BS0 : BS1;
            ushort_t* const BSc = cur ? BS1 : BS0;
            asm volatile("s_waitcnt vmcnt(2)" ::: "memory");
            const int kb = (t << 5) + ((lane & 3) << 3);
            float4 psa = *(const float4*)&psS[kb];
            float4 psb = *(const float4*)&psS[kb + 4];
            float4 pfa = *(const float4*)&pfS[kb];
            float4 pfb = *(const float4*)&pfS[kb + 4];
            float ps[8] = {psa.x, psa.y, psa.z, psa.w, psb.x, psb.y, psb.z, psb.w};
            float pf[8] = {pfa.x, pfa.y, pfa.z, pfa.w, pfb.x, pfb.y, pfb.z, pfb.w};
            bf16x8 w0, w1;
            const ushort_t* u0 = (const ushort_t*)&ar0;
            const ushort_t* u1 = (const ushort_t*)&ar1;
#pragma unroll
            for (int j = 0; j < 8; ++j) {
                float v0 = b2f(u0[j]) * ps[j] + pf[j];
                float v1 = b2f(u1[j]) * ps[j] + pf[j];
                w0[j] = (short)f2b(v0 > 0.f ? v0 : 0.f);
                w1[j] = (short)f2b(v1 > 0.f ? v1 : 0.f);
            }
            ushort_t* dA = ASc + ((wave << 5) + srow) * 32 + schunk;
            *(bf16x8*)dA = w0;
            *(bf16x8*)(dA + 16 * 32) = w1;
            if (t + 1 < NT) {
                ar0 = *(const uint4*)aNext;
                ar1 = *(const uint4*)(aNext + a16);
                gl_lds16(bNext, BSn + ldsW);
                gl_lds16(bNext + b16, BSn + ldsW + 512);
                aNext += 32; bNext += 32;
                asm volatile("s_waitcnt vmcnt(4) lgkmcnt(0)" ::: "memory");
            } else {
                asm volatile("s_waitcnt vmcnt(0) lgkmcnt(0)" ::: "memory");
            }
            __builtin_amdgcn_s_barrier();
            __builtin_amdgcn_sched_barrier(0);

            bf16x8 af[4], bf[4];
#pragma unroll
            for (int mi = 0; mi < 4; ++mi)
                af[mi] = *(const bf16x8*)&ASc[((wm << 6) + (mi << 4) + fr) * 32 + rdoff];
#pragma unroll
            for (int nj = 0; nj < 4; ++nj)
                bf[nj] = *(const bf16x8*)&BSc[((wn << 6) + (nj << 4) + fr) * 32 + rdoff];
#pragma unroll
            for (int mi = 0; mi < 4; ++mi)
#pragma unroll
                for (int nj = 0; nj < 4; ++nj)
                    acc[mi][nj] = __builtin_amdgcn_mfma_f32_16x16x32_bf16(af[mi], bf[nj], acc[mi][nj], 0, 0, 0);

            __builtin_amdgcn_sched_barrier(0);
            __builtin_amdgcn_s_barrier();
            cur ^= 1;
        }
    }

    // ---- stats from acc: race-free partial writes (NO atomics)
    if (STATS) {
        float s1[4] = {0.f, 0.f, 0.f, 0.f}, s2[4] = {0.f, 0.f, 0.f, 0.f};
#pragma unroll
        for (int nj = 0; nj < 4; ++nj) {
            const int col = n0 + (wn << 6) + (nj << 4) + fr;
            if (col < N) {
                const float bv = bias[col];
#pragma unroll
                for (int mi = 0; mi < 4; ++mi) {
                    const int rbase = m0 + (wm << 6) + (mi << 4) + (fq << 2);
#pragma unroll
                    for (int r = 0; r < 4; ++r) {
                        if (rbase + r < M) {
                            float v = acc[mi][nj][r] + bv;
                            if (RELU) v = v > 0.f ? v : 0.f;
                            s1[nj] += v; s2[nj] += v * v;
                        }
                    }
                }
            }
        }
#pragma unroll
        for (int nj = 0; nj < 4; ++nj) {
            s1[nj] += __shfl_xor(s1[nj], 16);
            s1[nj] += __shfl_xor(s1[nj], 32);
            s2[nj] += __shfl_xor(s2[nj], 16);
            s2[nj] += __shfl_xor(s2[nj], 32);
        }
        if (lane < 16) {
            float* pw = partials + (size_t)(mt * 2 + wm) * 2 * 640;
#pragma unroll
            for (int nj = 0; nj < 4; ++nj) {
                const int col = n0 + (wn << 6) + (nj << 4) + lane;
                if (col < N) {
                    pw[col] = s1[nj];
                    pw[640 + col] = s2[nj];
                }
            }
        }
    }

    // ---- epilogue: acc -> LDS C-tile -> coalesced full-line global stores
    __syncthreads();
    if (OUT_BF16) {
        ushort_t* ct = sh;
#pragma unroll
        for (int nj = 0; nj < 4; ++nj) {
            const int col_l = (wn << 6) + (nj << 4) + fr;
            const int col = n0 + col_l;
            const float bv = (col < N) ? bias[col] : 0.f;
#pragma unroll
            for (int mi = 0; mi < 4; ++mi) {
                const int rl0 = (wm << 6) + (mi << 4) + (fq << 2);
#pragma unroll
                for (int r = 0; r < 4; ++r) {
                    float v = acc[mi][nj][r] + bv;
                    if (RELU) v = v > 0.f ? v : 0.f;
                    ct[(rl0 + r) * CSTR + col_l] = f2b(v);
                }
            }
        }
        __syncthreads();
        const int rr = tid >> 1, half = tid & 1;
        const int grow = m0 + rr;
        if (grow < M) {
            const ushort_t* src = ct + rr * CSTR + (half << 6);
            ushort_t* dst = (ushort_t*)C + (size_t)grow * ldc + n0 + (half << 6);
#pragma unroll
            for (int c = 0; c < 8; ++c) {
                const int gc = n0 + (half << 6) + (c << 3);
                if (gc + 7 < N) {
                    uint2 u0 = *(const uint2*)(src + (c << 3));
                    uint2 u1 = *(const uint2*)(src + (c << 3) + 4);
                    uint4 o; o.x = u0.x; o.y = u0.y; o.z = u1.x; o.w = u1.y;
                    *(uint4*)(dst + (c << 3)) = o;
                } else {
                    for (int j = 0; j < 8; ++j)
                        if (gc + j < N) dst[(c << 3) + j] = src[(c << 3) + j];
                }
            }
        }
    } else {
        float* ctf = (float*)sh;
#pragma unroll
        for (int ph = 0; ph < 2; ++ph) {
            if (wm == ph) {
#pragma unroll
                for (int nj = 0; nj < 4; ++nj) {
                    const int col_l = (wn << 6) + (nj << 4) + fr;
                    const int col = n0 + col_l;
                    const float bv = (col < N) ? bias[col] : 0.f;
#pragma unroll
                    for (int mi = 0; mi < 4; ++mi) {
                        const int rl0 = (mi << 4) + (fq << 2);
#pragma unroll
                        for (int r = 0; r < 4; ++r) {
                            float v = acc[mi][nj][r] + bv;
                            if (RELU) v = v > 0.f ? v : 0.f;
                            ctf[(rl0 + r) * CSTR + col_l] = v;
                        }
                    }
                }
            }
            __syncthreads();
            const int rr = tid >> 2, q = tid & 3;
            const int grow = m0 + (ph << 6) + rr;
            if (grow < M) {
                const float* src = ctf + rr * CSTR + (q << 5);
                float* dst = (float*)C + (size_t)grow * ldc + n0 + (q << 5);
#pragma unroll
                for (int c = 0; c < 8; ++c) {
                    const int gc = n0 + (q << 5) + (c << 2);
                    if (gc + 3 < N) {
                        *(float4*)(dst + (c << 2)) = *(const float4*)(src + (c << 2));
                    } else {
                        for (int j = 0; j < 4; ++j)
                            if (gc + j < N) dst[(c << 2) + j] = src[(c << 2) + j];
                    }
                }
            }
            __syncthreads();
        }
    }
}

// ---------------- BN reduce + finalize: partials -> pscale/pshift ----------------
__global__ __launch_bounds__(256) void bn_reduce(
    const float* __restrict__ partials, const float* __restrict__ gamma,
    const float* __restrict__ beta, float* __restrict__ pscale,
    float* __restrict__ pshift, float invM) {
    const int c = blockIdx.x;  // 0..HID-1
    const int t = threadIdx.x;
    float s1 = 0.f, s2 = 0.f;
    for (int i = t; i < MT_TILES * 2; i += 256) {
        const float* pw = partials + (size_t)i * 2 * 640;
        s1 += pw[c];
        s2 += pw[640 + c];
    }
    __shared__ float r1[256], r2[256];
    r1[t] = s1; r2[t] = s2;
    __syncthreads();
    for (int off = 128; off > 0; off >>= 1) {
        if (t < off) { r1[t] += r1[t + off]; r2[t] += r2[t + off]; }
        __syncthreads();
    }
    if (t == 0) {
        float mu = r1[0] * invM;
        float var = r2[0] * invM - mu * mu;
        float rs = rsqrtf(var + BN_EPS);
        float g = gamma[c] * rs;
        pscale[c] = g;
        pshift[c] = beta[c] - mu * g;
    }
}

extern "C" void kernel_launch(void* const* d_in, const int* in_sizes, int n_in,
                              void* d_out, int out_size, void* d_ws, size_t ws_size,
                              hipStream_t stream) {
    const float* x = (const float*)d_in[0];
    const int* ei = (const int*)d_in[1];
    const float* lin_in_w = (const float*)d_in[3];
    const float* lin_in_b = (const float*)d_in[4];
    const float* w1 = (const float*)d_in[5];
    const float* b1 = (const float*)d_in[6];
    const float* gamma = (const float*)d_in[7];
    const float* beta = (const float*)d_in[8];
    const float* w2 = (const float*)d_in[9];
    const float* b2 = (const float*)d_in[10];
    float* out = (float*)d_out;

    char* p = (char*)d_ws;
    auto alloc = [&](size_t bytes) {
        char* r = p;
        p += (bytes + 255) & ~(size_t)255;
        return r;
    };
    ushort_t* xb  = (ushort_t*)alloc((size_t)MPAD * K0P * 2);
    ushort_t* h   = (ushort_t*)alloc((size_t)MPAD * K1P * 2);
    ushort_t* agg = (ushort_t*)alloc((size_t)MPAD * K1P * 2);
    ushort_t* z   = (ushort_t*)alloc((size_t)MPAD * K2P * 2);
    ushort_t* lint = (ushort_t*)alloc((size_t)N0P * K0P * 2);
    ushort_t* w1t  = (ushort_t*)alloc((size_t)NLAYERS * N1P * K1P * 2);
    ushort_t* w2t  = (ushort_t*)alloc((size_t)NLAYERS * N0P * K2P * 2);
    int* deg    = (int*)alloc(NNODES * 4);
    int* cursor = (int*)alloc(NNODES * 4);
    int* offs   = (int*)alloc((NNODES + 1) * 4);
    int* bsum   = (int*)alloc(1024);
    int* csr    = (int*)alloc((size_t)NEDGES * 4);
    int* bh     = (int*)alloc((size_t)NBH * 256 * 4);   // 200 KB block-histograms
    int* perm   = (int*)alloc(NNODES * 4);
    float* partials = (float*)alloc((size_t)MT_TILES * 2 * 2 * 640 * 4);  // 4.0 MB
    float* pscale = (float*)alloc(HID * 4);
    float* pshift = (float*)alloc(HID * 4);
    int* mode   = (int*)alloc(256);
    (void)ws_size; (void)in_sizes; (void)n_in; (void)out_size;

    hipMemsetAsync(deg, 0, NNODES * 4, stream);
    hipMemsetAsync(h + (size_t)NNODES * K1P, 0, (size_t)(MPAD - NNODES) * K1P * 2, stream);

    // CSR build
    detect_mode_kernel<<<1, 64, 0, stream>>>((const unsigned int*)ei, mode);
    hist_kernel<<<(NEDGES + 255) / 256, 256, 0, stream>>>(ei, mode, deg);
    const int nb = (NNODES + 255) / 256;  // == NBH
    scan_block_sums<<<nb, 256, 0, stream>>>(deg, bsum, NNODES);
    scan_bsums<<<1, 256, 0, stream>>>(bsum, nb);
    scan_final<<<nb, 256, 0, stream>>>(deg, bsum, offs, cursor, NNODES);
    fill_csr<<<(NEDGES + 255) / 256, 256, 0, stream>>>(ei, mode, cursor, csr);

    // contention-free degree counting sort (once; reused by all 5 aggregates)
    deg_hist_lds<<<NBH, 256, 0, stream>>>(offs, bh);
    deg_scan2<<<1, 256, 0, stream>>>(bh);
    deg_scatter_lds<<<NBH, 256, 0, stream>>>(offs, bh, perm);

    // conversions
    cast_x_kernel<<<(NNODES * 32 + 255) / 256, 256, 0, stream>>>(x, xb);
    conv_lin_kernel<<<(N0P * K0P + 255) / 256, 256, 0, stream>>>(lin_in_w, lint);
    conv_w1_kernel<<<(NLAYERS * N1P * K1P + 255) / 256, 256, 0, stream>>>(w1, w1t);
    conv_w2_kernel<<<(NLAYERS * N0P * K2P + 255) / 256, 256, 0, stream>>>(w2, w2t);

    // XCD-colocated 1D grids: 8 * ceil(391/8) * NB
    const int G3 = 8 * 49 * 3;  // 1176
    const int G5 = 8 * 49 * 5;  // 1960

    // input linear: h = x @ lin_in_w + b  (bf16 out)
    gemm_mfma<0, 0, 0, 1><<<G3, 256, 0, stream>>>(
        xb, K0P, lint, K0P, lin_in_b, h, K1P, NNODES, EMB, K0P,
        nullptr, nullptr, 0, nullptr, 3);

    for (int l = 0; l < NLAYERS; ++l) {
        aggregate_bf16<<<(NNODES / 2 + 3) / 4, 256, 0, stream>>>(h, agg, offs, csr, perm);
        // z = agg @ w1[l] + b1[l]  (bf16 out + race-free partial col stats)
        gemm_mfma<0, 0, 1, 1><<<G5, 256, 0, stream>>>(
            agg, K1P, w1t + (size_t)l * N1P * K1P, K1P, b1 + (size_t)l * HID,
            z, K2P, NNODES, HID, K1P,
            nullptr, nullptr, 0, partials, 5);
        bn_reduce<<<HID, 256, 0, stream>>>(
            partials, gamma + (size_t)l * HID, beta + (size_t)l * HID,
            pscale, pshift, 1.f / NNODES);
        // h_new = relu?( relu(BN(z)) @ w2[l] + b2[l] )  — BN+ReLU fused into A staging
        if (l < NLAYERS - 1) {
            gemm_mfma<1, 1, 0, 1><<<G3, 256, 0, stream>>>(
                z, K2P, w2t + (size_t)l * N0P * K2P, K2P, b2 + (size_t)l * EMB,
                h, K1P, NNODES, EMB, K2P,
                pscale, pshift, HID, nullptr, 3);
        } else {
            gemm_mfma<1, 0, 0, 0><<<G3, 256, 0, stream>>>(
                z, K2P, w2t + (size_t)l * N0P * K2P, K2P, b2 + (size_t)l * EMB,
                out, EMB, NNODES, EMB, K2P,
                pscale, pshift, HID, nullptr, 3);
        }
    }
}

// Round 15
// 1104.773 us; speedup vs baseline: 1.0224x; 1.0224x over previous
//
#include <hip/hip_runtime.h>
#include <cstdint>
#include <cstddef>

#define NNODES 50000
#define NEDGES 800000
#define IN_DIM 232
#define EMB 300
#define HID 600
#define NLAYERS 5
#define BN_EPS 1e-5f

#define MPAD 50048        // 391 * 128
#define K0P 256           // IN_DIM 232 -> 256
#define K1P 320           // EMB 300 -> 320
#define K2P 608           // HID 600 -> 608
#define N0P 384           // EMB out tiles (3 x 128)
#define N1P 640           // HID out tiles (5 x 128)
#define MT_TILES 391      // MPAD / 128
#define CSTR 140          // epilogue LDS C-tile row stride (elems)

typedef unsigned short ushort_t;
typedef __attribute__((ext_vector_type(8))) short bf16x8;
typedef __attribute__((ext_vector_type(4))) float f32x4;

__device__ __forceinline__ float b2f(ushort_t u) {
    unsigned int x = (unsigned int)u << 16;
    return __builtin_bit_cast(float, x);
}
__device__ __forceinline__ ushort_t f2b(float f) {
    unsigned int x = __builtin_bit_cast(unsigned int, f);
    unsigned int r = (x + 0x7fffu + ((x >> 16) & 1u)) >> 16;
    return (ushort_t)r;
}

__device__ __forceinline__ void gl_lds16(const void* gsrc, void* ldst) {
    __builtin_amdgcn_global_load_lds(
        (const __attribute__((address_space(1))) void*)gsrc,
        (__attribute__((address_space(3))) void*)ldst, 16, 0, 0);
}

// ---------------- edge-index dtype detection (int64 vs int32) ----------------
__global__ void detect_mode_kernel(const unsigned int* __restrict__ ei, int* __restrict__ mode) {
    if (threadIdx.x == 0 && blockIdx.x == 0) {
        int nz = 0;
        for (int i = 0; i < 256; ++i) nz += (ei[2 * i + 1] != 0u);
        *mode = (nz == 0) ? 1 : 0;
    }
}
__device__ __forceinline__ int load_edge(const int* ei, int mode, long long idx) {
    if (mode) return (int)((const long long*)ei)[idx];
    return ei[idx];
}

// ---------------- CSR build ----------------
__global__ void hist_kernel(const int* __restrict__ ei, const int* __restrict__ mode,
                            int* __restrict__ deg) {
    int i = blockIdx.x * blockDim.x + threadIdx.x;
    if (i >= NEDGES) return;
    int d = load_edge(ei, *mode, (long long)NEDGES + i);
    atomicAdd(&deg[d], 1);
}

__global__ void scan_block_sums(const int* __restrict__ deg, int* __restrict__ bsum, int n) {
    __shared__ int s[256];
    int t = threadIdx.x;
    int i = blockIdx.x * 256 + t;
    s[t] = (i < n) ? deg[i] : 0;
    __syncthreads();
    for (int off = 128; off > 0; off >>= 1) {
        if (t < off) s[t] += s[t + off];
        __syncthreads();
    }
    if (t == 0) bsum[blockIdx.x] = s[0];
}

__global__ void scan_bsums(int* __restrict__ bsum, int nb) {
    __shared__ int s[256];
    int t = threadIdx.x;
    int v = (t < nb) ? bsum[t] : 0;
    s[t] = v;
    __syncthreads();
    for (int off = 1; off < 256; off <<= 1) {
        int u = (t >= off) ? s[t - off] : 0;
        __syncthreads();
        s[t] += u;
        __syncthreads();
    }
    if (t < nb) bsum[t] = s[t] - v;  // exclusive
}

__global__ void scan_final(const int* __restrict__ deg, const int* __restrict__ bsum,
                           int* __restrict__ offs, int* __restrict__ cursor, int n) {
    __shared__ int s[256];
    int t = threadIdx.x;
    int i = blockIdx.x * 256 + t;
    int v = (i < n) ? deg[i] : 0;
    s[t] = v;
    __syncthreads();
    for (int off = 1; off < 256; off <<= 1) {
        int u = (t >= off) ? s[t - off] : 0;
        __syncthreads();
        s[t] += u;
        __syncthreads();
    }
    int excl = s[t] - v + bsum[blockIdx.x];
    if (i < n) {
        offs[i] = excl;
        cursor[i] = excl;
        if (i == n - 1) offs[n] = excl + v;
    }
}

__global__ void fill_csr(const int* __restrict__ ei, const int* __restrict__ mode,
                         int* __restrict__ cursor, int* __restrict__ csr) {
    int i = blockIdx.x * blockDim.x + threadIdx.x;
    if (i >= NEDGES) return;
    int m = *mode;
    int s = load_edge(ei, m, i);
    int d = load_edge(ei, m, (long long)NEDGES + i);
    int p = atomicAdd(&cursor[d], 1);
    csr[p] = s;
}

// ---------------- conversions ----------------
// x [50000][232] f32 -> xb [MPAD][256] bf16, vectorized (232 = 29*8 exactly).
__global__ __launch_bounds__(256) void cast_x_kernel(const float* __restrict__ x,
                                                     ushort_t* __restrict__ o) {
    int idx = blockIdx.x * 256 + threadIdx.x;
    if (idx >= NNODES * 32) return;
    int row = idx >> 5, g = idx & 31;
    ushort_t* dst = o + (size_t)row * K0P + g * 8;
    if (g < 29) {
        const float* src = x + (size_t)row * IN_DIM + g * 8;
        float4 a = *(const float4*)src;
        float4 b = *(const float4*)(src + 4);
        ushort_t tmp[8] = {f2b(a.x), f2b(a.y), f2b(a.z), f2b(a.w),
                           f2b(b.x), f2b(b.y), f2b(b.z), f2b(b.w)};
        *(uint4*)dst = *(const uint4*)tmp;
    } else {
        uint4 zz = {0, 0, 0, 0};
        *(uint4*)dst = zz;
    }
}

// LDS-tiled transpose+cast: src [L][Kin][Nin] f32 (row-major, n fastest)
// -> dst [L][Nout][Kout] bf16 with dst[l][n][k] = src[l][k][n], zero-padded.
// 32x32 tile via LDS [32][33]; both global sides coalesced.
__global__ __launch_bounds__(256) void transpose_w(
    const float* __restrict__ src, ushort_t* __restrict__ dst,
    int Kin, int Nin, int Kout, int Nout) {
    __shared__ float tile[32][33];
    const int l = blockIdx.z;
    const int k0 = blockIdx.x << 5, n0 = blockIdx.y << 5;
    const int tx = threadIdx.x & 31, ty = threadIdx.x >> 5;  // ty 0..7
    const float* s = src + (size_t)l * Kin * Nin;
    ushort_t* d = dst + (size_t)l * Nout * Kout;
#pragma unroll
    for (int r = 0; r < 32; r += 8) {
        const int k = k0 + ty + r, n = n0 + tx;
        tile[ty + r][tx] = (k < Kin && n < Nin) ? s[(size_t)k * Nin + n] : 0.f;
    }
    __syncthreads();
#pragma unroll
    for (int r = 0; r < 32; r += 8) {
        const int n = n0 + ty + r, k = k0 + tx;
        if (n < Nout && k < Kout) d[(size_t)n * Kout + k] = f2b(tile[tx][ty + r]);
    }
}

// ---------------- aggregation: dual-chain + 4-deep in-chain unroll (round-10/13) -------
// agg[v] = h[v] + sum_{u in N_in(v)} h[u]; h/agg are [MPAD][320] bf16, pad cols zeroed.
__global__ __launch_bounds__(256) void aggregate_bf16(
    const ushort_t* __restrict__ h, ushort_t* __restrict__ agg,
    const int* __restrict__ offs, const int* __restrict__ csr) {
    const int w = blockIdx.x * 4 + (threadIdx.x >> 6);
    const int lane = threadIdx.x & 63;
    const int wid0 = w * 2, wid1 = wid0 + 1;
    if (wid0 >= NNODES) return;  // NNODES even -> wid1 always valid
    const bool hasb = lane < 11;  // slots 64..74 (cols 256..299)
    float a0[4], a1[4] = {0.f, 0.f, 0.f, 0.f};
    float c0[4], c1[4] = {0.f, 0.f, 0.f, 0.f};
    {
        const ushort4* r0 = (const ushort4*)(h + (size_t)wid0 * K1P);
        const ushort4* r1 = (const ushort4*)(h + (size_t)wid1 * K1P);
        ushort4 v0 = r0[lane], v1 = r1[lane];
        a0[0] = b2f(v0.x); a0[1] = b2f(v0.y); a0[2] = b2f(v0.z); a0[3] = b2f(v0.w);
        c0[0] = b2f(v1.x); c0[1] = b2f(v1.y); c0[2] = b2f(v1.z); c0[3] = b2f(v1.w);
        if (hasb) {
            ushort4 w0 = r0[64 + lane], w1 = r1[64 + lane];
            a1[0] = b2f(w0.x); a1[1] = b2f(w0.y); a1[2] = b2f(w0.z); a1[3] = b2f(w0.w);
            c1[0] = b2f(w1.x); c1[1] = b2f(w1.y); c1[2] = b2f(w1.z); c1[3] = b2f(w1.w);
        }
    }
    int p0 = offs[wid0], e0 = offs[wid0 + 1];
    int p1 = e0, e1 = offs[wid1 + 1];  // offs[wid0+1] == offs[wid1]

    // ---- 4-deep unrolled main loop (both chains have >= 4 edges left)
    while (p0 + 4 <= e0 && p1 + 4 <= e1) {
        int s0[4], s1[4];
#pragma unroll
        for (int u = 0; u < 4; ++u) { s0[u] = csr[p0 + u]; s1[u] = csr[p1 + u]; }
        ushort4 x0[4], x1[4], y0[4], y1[4];
#pragma unroll
        for (int u = 0; u < 4; ++u) {
            const ushort4* r0 = (const ushort4*)(h + (size_t)s0[u] * K1P);
            const ushort4* r1 = (const ushort4*)(h + (size_t)s1[u] * K1P);
            x0[u] = r0[lane];
            x1[u] = r1[lane];
            if (hasb) { y0[u] = r0[64 + lane]; y1[u] = r1[64 + lane]; }
        }
#pragma unroll
        for (int u = 0; u < 4; ++u) {
            a0[0] += b2f(x0[u].x); a0[1] += b2f(x0[u].y); a0[2] += b2f(x0[u].z); a0[3] += b2f(x0[u].w);
            c0[0] += b2f(x1[u].x); c0[1] += b2f(x1[u].y); c0[2] += b2f(x1[u].z); c0[3] += b2f(x1[u].w);
            if (hasb) {
                a1[0] += b2f(y0[u].x); a1[1] += b2f(y0[u].y); a1[2] += b2f(y0[u].z); a1[3] += b2f(y0[u].w);
                c1[0] += b2f(y1[u].x); c1[1] += b2f(y1[u].y); c1[2] += b2f(y1[u].z); c1[3] += b2f(y1[u].w);
            }
        }
        p0 += 4; p1 += 4;
    }

    // ---- dual-chain single-step remainder
    while (p0 < e0 && p1 < e1) {
        const ushort4* r0 = (const ushort4*)(h + (size_t)csr[p0] * K1P); ++p0;
        const ushort4* r1 = (const ushort4*)(h + (size_t)csr[p1] * K1P); ++p1;
        ushort4 v0 = r0[lane];
        ushort4 v1 = r1[lane];
        a0[0] += b2f(v0.x); a0[1] += b2f(v0.y); a0[2] += b2f(v0.z); a0[3] += b2f(v0.w);
        c0[0] += b2f(v1.x); c0[1] += b2f(v1.y); c0[2] += b2f(v1.z); c0[3] += b2f(v1.w);
        if (hasb) {
            ushort4 w0 = r0[64 + lane];
            ushort4 w1 = r1[64 + lane];
            a1[0] += b2f(w0.x); a1[1] += b2f(w0.y); a1[2] += b2f(w0.z); a1[3] += b2f(w0.w);
            c1[0] += b2f(w1.x); c1[1] += b2f(w1.y); c1[2] += b2f(w1.z); c1[3] += b2f(w1.w);
        }
    }
    while (p0 < e0) {
        const ushort4* r0 = (const ushort4*)(h + (size_t)csr[p0] * K1P); ++p0;
        ushort4 v0 = r0[lane];
        a0[0] += b2f(v0.x); a0[1] += b2f(v0.y); a0[2] += b2f(v0.z); a0[3] += b2f(v0.w);
        if (hasb) {
            ushort4 w0 = r0[64 + lane];
            a1[0] += b2f(w0.x); a1[1] += b2f(w0.y); a1[2] += b2f(w0.z); a1[3] += b2f(w0.w);
        }
    }
    while (p1 < e1) {
        const ushort4* r1 = (const ushort4*)(h + (size_t)csr[p1] * K1P); ++p1;
        ushort4 v1 = r1[lane];
        c0[0] += b2f(v1.x); c0[1] += b2f(v1.y); c0[2] += b2f(v1.z); c0[3] += b2f(v1.w);
        if (hasb) {
            ushort4 w1 = r1[64 + lane];
            c1[0] += b2f(w1.x); c1[1] += b2f(w1.y); c1[2] += b2f(w1.z); c1[3] += b2f(w1.w);
        }
    }
    ushort4* o0 = (ushort4*)(agg + (size_t)wid0 * K1P);
    ushort4* o1 = (ushort4*)(agg + (size_t)wid1 * K1P);
    ushort4 ov;
    ov.x = f2b(a0[0]); ov.y = f2b(a0[1]); ov.z = f2b(a0[2]); ov.w = f2b(a0[3]);
    o0[lane] = ov;
    ov.x = f2b(c0[0]); ov.y = f2b(c0[1]); ov.z = f2b(c0[2]); ov.w = f2b(c0[3]);
    o1[lane] = ov;
    if (hasb) {
        ov.x = f2b(a1[0]); ov.y = f2b(a1[1]); ov.z = f2b(a1[2]); ov.w = f2b(a1[3]);
        o0[64 + lane] = ov;
        ov.x = f2b(c1[0]); ov.y = f2b(c1[1]); ov.z = f2b(c1[2]); ov.w = f2b(c1[3]);
        o1[64 + lane] = ov;
    }
    if (lane < 5) {  // zero K-pad cols 300..319
        ushort4 zz; zz.x = zz.y = zz.z = zz.w = 0;
        o0[75 + lane] = zz;
        o1[75 + lane] = zz;
    }
}

// ---------------- bf16 MFMA GEMM + XCD colocation (round-13 structure) ----------
// C = pro(A)[M,K] @ Bt[N,K]^T + bias.  128x128 tile, BK=32, 4 waves (2x2 of 64x64).
// Non-PRO: QUAD-buffered LDS, 2-ahead prefetch, one barrier per K-step.
// PRO (BN+ReLU fused on A): LDS double-buffer, 1-ahead.
// STATS: race-free per-(mt,wm) partial col sums (NO atomics), reduced by bn_reduce.
template <int PRO, int RELU, int STATS, int OUT_BF16>
__global__ __launch_bounds__(256) void gemm_mfma(
    const ushort_t* __restrict__ A, int lda,
    const ushort_t* __restrict__ Bt, int ldb,
    const float* __restrict__ bias,
    void* __restrict__ C, int ldc, int M, int N, int K,
    const float* __restrict__ pscale, const float* __restrict__ pshift, int Kreal,
    float* __restrict__ partials, int NB) {
    __shared__ ushort_t sh[PRO ? 17920 : 32768];
    __shared__ float psS[PRO ? 640 : 4];
    __shared__ float pfS[PRO ? 640 : 4];

    const int bid = blockIdx.x;
    const int xcd = bid & 7, slot = bid >> 3;
    const int mt = (slot / NB) * 8 + xcd;
    if (mt >= MT_TILES) return;
    const int nt = slot % NB;
    const int m0 = mt << 7, n0 = nt << 7;

    const int tid = threadIdx.x;
    const int wave = tid >> 6, lane = tid & 63;
    const int wm = wave >> 1, wn = wave & 1;
    const int NT = K >> 5;

    const int srow = lane >> 2;
    const int schunk = ((lane & 3) ^ ((lane >> 3) & 3)) << 3;
    const ushort_t* bP = Bt + (size_t)(n0 + (wave << 5) + srow) * ldb + schunk;
    const ushort_t* aPg = A + (size_t)(m0 + (wave << 5) + srow) * lda + schunk;
    const ushort_t* aPr = A + (size_t)(m0 + (wave << 5) + srow) * lda + ((lane & 3) << 3);
    const int a16 = lda << 4, b16 = ldb << 4;
    const int ldsW = wave << 10;

    const int fr = lane & 15, fq = lane >> 4;
    const int rdoff = (fq ^ ((fr >> 1) & 3)) << 3;

    f32x4 acc[4][4];
#pragma unroll
    for (int i = 0; i < 4; ++i)
#pragma unroll
        for (int j = 0; j < 4; ++j) acc[i][j] = {0.f, 0.f, 0.f, 0.f};

    if (PRO) {
        for (int i = tid; i < 640; i += 256) {
            psS[i] = (i < Kreal) ? pscale[i] : 0.f;
            pfS[i] = (i < Kreal) ? pshift[i] : 0.f;
        }
        __syncthreads();
    }

    if (!PRO) {
        const ushort_t* aN = aPg;
        const ushort_t* bN = bP;
        gl_lds16(aN, sh + ldsW);
        gl_lds16(aN + a16, sh + ldsW + 512);
        gl_lds16(bN, sh + 16384 + ldsW);
        gl_lds16(bN + b16, sh + 16384 + ldsW + 512);
        aN += 32; bN += 32;
        gl_lds16(aN, sh + 4096 + ldsW);
        gl_lds16(aN + a16, sh + 4096 + ldsW + 512);
        gl_lds16(bN, sh + 20480 + ldsW);
        gl_lds16(bN + b16, sh + 20480 + ldsW + 512);
        aN += 32; bN += 32;

        for (int t = 0; t < NT; ++t) {
            const int cb = t & 3;
            if (t + 2 < NT) {
                const int sb = (t + 2) & 3;
                gl_lds16(aN, sh + (sb << 12) + ldsW);
                gl_lds16(aN + a16, sh + (sb << 12) + ldsW + 512);
                gl_lds16(bN, sh + 16384 + (sb << 12) + ldsW);
                gl_lds16(bN + b16, sh + 16384 + (sb << 12) + ldsW + 512);
                aN += 32; bN += 32;
                asm volatile("s_waitcnt vmcnt(8)" ::: "memory");
            } else if (t + 1 < NT) {
                asm volatile("s_waitcnt vmcnt(4)" ::: "memory");
            } else {
                asm volatile("s_waitcnt vmcnt(0)" ::: "memory");
            }
            __builtin_amdgcn_s_barrier();
            __builtin_amdgcn_sched_barrier(0);

            const ushort_t* ASc = sh + (cb << 12);
            const ushort_t* BSc = sh + 16384 + (cb << 12);
            bf16x8 af[4], bf[4];
#pragma unroll
            for (int mi = 0; mi < 4; ++mi)
                af[mi] = *(const bf16x8*)&ASc[((wm << 6) + (mi << 4) + fr) * 32 + rdoff];
#pragma unroll
            for (int nj = 0; nj < 4; ++nj)
                bf[nj] = *(const bf16x8*)&BSc[((wn << 6) + (nj << 4) + fr) * 32 + rdoff];
#pragma unroll
            for (int mi = 0; mi < 4; ++mi)
#pragma unroll
                for (int nj = 0; nj < 4; ++nj)
                    acc[mi][nj] = __builtin_amdgcn_mfma_f32_16x16x32_bf16(af[mi], bf[nj], acc[mi][nj], 0, 0, 0);

            __builtin_amdgcn_sched_barrier(0);
        }
    } else {
        ushort_t* const AS0 = sh;
        ushort_t* const AS1 = sh + 4096;
        ushort_t* const BS0 = sh + 8192;
        ushort_t* const BS1 = sh + 12288;
        uint4 ar0, ar1;
        const ushort_t* aNext;
        const ushort_t* bNext = bP + 32;
        ar0 = *(const uint4*)aPr;
        ar1 = *(const uint4*)(aPr + a16);
        gl_lds16(bP, BS0 + ldsW);
        gl_lds16(bP + b16, BS0 + ldsW + 512);
        aNext = aPr + 32;

        int cur = 0;
        for (int t = 0; t < NT; ++t) {
            ushort_t* const ASc = cur ? AS1 : AS0;
            ushort_t* const BSn = cur ? BS0 : BS1;
            ushort_t* const BSc = cur ? BS1 : BS0;
            asm volatile("s_waitcnt vmcnt(2)" ::: "memory");
            const int kb = (t << 5) + ((lane & 3) << 3);
            float4 psa = *(const float4*)&psS[kb];
            float4 psb = *(const float4*)&psS[kb + 4];
            float4 pfa = *(const float4*)&pfS[kb];
            float4 pfb = *(const float4*)&pfS[kb + 4];
            float ps[8] = {psa.x, psa.y, psa.z, psa.w, psb.x, psb.y, psb.z, psb.w};
            float pf[8] = {pfa.x, pfa.y, pfa.z, pfa.w, pfb.x, pfb.y, pfb.z, pfb.w};
            bf16x8 w0, w1;
            const ushort_t* u0 = (const ushort_t*)&ar0;
            const ushort_t* u1 = (const ushort_t*)&ar1;
#pragma unroll
            for (int j = 0; j < 8; ++j) {
                float v0 = b2f(u0[j]) * ps[j] + pf[j];
                float v1 = b2f(u1[j]) * ps[j] + pf[j];
                w0[j] = (short)f2b(v0 > 0.f ? v0 : 0.f);
                w1[j] = (short)f2b(v1 > 0.f ? v1 : 0.f);
            }
            ushort_t* dA = ASc + ((wave << 5) + srow) * 32 + schunk;
            *(bf16x8*)dA = w0;
            *(bf16x8*)(dA + 16 * 32) = w1;
            if (t + 1 < NT) {
                ar0 = *(const uint4*)aNext;
                ar1 = *(const uint4*)(aNext + a16);
                gl_lds16(bNext, BSn + ldsW);
                gl_lds16(bNext + b16, BSn + ldsW + 512);
                aNext += 32; bNext += 32;
                asm volatile("s_waitcnt vmcnt(4) lgkmcnt(0)" ::: "memory");
            } else {
                asm volatile("s_waitcnt vmcnt(0) lgkmcnt(0)" ::: "memory");
            }
            __builtin_amdgcn_s_barrier();
            __builtin_amdgcn_sched_barrier(0);

            bf16x8 af[4], bf[4];
#pragma unroll
            for (int mi = 0; mi < 4; ++mi)
                af[mi] = *(const bf16x8*)&ASc[((wm << 6) + (mi << 4) + fr) * 32 + rdoff];
#pragma unroll
            for (int nj = 0; nj < 4; ++nj)
                bf[nj] = *(const bf16x8*)&BSc[((wn << 6) + (nj << 4) + fr) * 32 + rdoff];
#pragma unroll
            for (int mi = 0; mi < 4; ++mi)
#pragma unroll
                for (int nj = 0; nj < 4; ++nj)
                    acc[mi][nj] = __builtin_amdgcn_mfma_f32_16x16x32_bf16(af[mi], bf[nj], acc[mi][nj], 0, 0, 0);

            __builtin_amdgcn_sched_barrier(0);
            __builtin_amdgcn_s_barrier();
            cur ^= 1;
        }
    }

    // ---- stats from acc: race-free partial writes (NO atomics)
    if (STATS) {
        float s1[4] = {0.f, 0.f, 0.f, 0.f}, s2[4] = {0.f, 0.f, 0.f, 0.f};
#pragma unroll
        for (int nj = 0; nj < 4; ++nj) {
            const int col = n0 + (wn << 6) + (nj << 4) + fr;
            if (col < N) {
                const float bv = bias[col];
#pragma unroll
                for (int mi = 0; mi < 4; ++mi) {
                    const int rbase = m0 + (wm << 6) + (mi << 4) + (fq << 2);
#pragma unroll
                    for (int r = 0; r < 4; ++r) {
                        if (rbase + r < M) {
                            float v = acc[mi][nj][r] + bv;
                            if (RELU) v = v > 0.f ? v : 0.f;
                            s1[nj] += v; s2[nj] += v * v;
                        }
                    }
                }
            }
        }
#pragma unroll
        for (int nj = 0; nj < 4; ++nj) {
            s1[nj] += __shfl_xor(s1[nj], 16);
            s1[nj] += __shfl_xor(s1[nj], 32);
            s2[nj] += __shfl_xor(s2[nj], 16);
            s2[nj] += __shfl_xor(s2[nj], 32);
        }
        if (lane < 16) {
            float* pw = partials + (size_t)(mt * 2 + wm) * 2 * 640;
#pragma unroll
            for (int nj = 0; nj < 4; ++nj) {
                const int col = n0 + (wn << 6) + (nj << 4) + lane;
                if (col < N) {
                    pw[col] = s1[nj];
                    pw[640 + col] = s2[nj];
                }
            }
        }
    }

    // ---- epilogue: acc -> LDS C-tile -> coalesced full-line global stores
    __syncthreads();
    if (OUT_BF16) {
        ushort_t* ct = sh;
#pragma unroll
        for (int nj = 0; nj < 4; ++nj) {
            const int col_l = (wn << 6) + (nj << 4) + fr;
            const int col = n0 + col_l;
            const float bv = (col < N) ? bias[col] : 0.f;
#pragma unroll
            for (int mi = 0; mi < 4; ++mi) {
                const int rl0 = (wm << 6) + (mi << 4) + (fq << 2);
#pragma unroll
                for (int r = 0; r < 4; ++r) {
                    float v = acc[mi][nj][r] + bv;
                    if (RELU) v = v > 0.f ? v : 0.f;
                    ct[(rl0 + r) * CSTR + col_l] = f2b(v);
                }
            }
        }
        __syncthreads();
        const int rr = tid >> 1, half = tid & 1;
        const int grow = m0 + rr;
        if (grow < M) {
            const ushort_t* src = ct + rr * CSTR + (half << 6);
            ushort_t* dst = (ushort_t*)C + (size_t)grow * ldc + n0 + (half << 6);
#pragma unroll
            for (int c = 0; c < 8; ++c) {
                const int gc = n0 + (half << 6) + (c << 3);
                if (gc + 7 < N) {
                    uint2 u0 = *(const uint2*)(src + (c << 3));
                    uint2 u1 = *(const uint2*)(src + (c << 3) + 4);
                    uint4 o; o.x = u0.x; o.y = u0.y; o.z = u1.x; o.w = u1.y;
                    *(uint4*)(dst + (c << 3)) = o;
                } else {
                    for (int j = 0; j < 8; ++j)
                        if (gc + j < N) dst[(c << 3) + j] = src[(c << 3) + j];
                }
            }
        }
    } else {
        float* ctf = (float*)sh;
#pragma unroll
        for (int ph = 0; ph < 2; ++ph) {
            if (wm == ph) {
#pragma unroll
                for (int nj = 0; nj < 4; ++nj) {
                    const int col_l = (wn << 6) + (nj << 4) + fr;
                    const int col = n0 + col_l;
                    const float bv = (col < N) ? bias[col] : 0.f;
#pragma unroll
                    for (int mi = 0; mi < 4; ++mi) {
                        const int rl0 = (mi << 4) + (fq << 2);
#pragma unroll
                        for (int r = 0; r < 4; ++r) {
                            float v = acc[mi][nj][r] + bv;
                            if (RELU) v = v > 0.f ? v : 0.f;
                            ctf[(rl0 + r) * CSTR + col_l] = v;
                        }
                    }
                }
            }
            __syncthreads();
            const int rr = tid >> 2, q = tid & 3;
            const int grow = m0 + (ph << 6) + rr;
            if (grow < M) {
                const float* src = ctf + rr * CSTR + (q << 5);
                float* dst = (float*)C + (size_t)grow * ldc + n0 + (q << 5);
#pragma unroll
                for (int c = 0; c < 8; ++c) {
                    const int gc = n0 + (q << 5) + (c << 2);
                    if (gc + 3 < N) {
                        *(float4*)(dst + (c << 2)) = *(const float4*)(src + (c << 2));
                    } else {
                        for (int j = 0; j < 4; ++j)
                            if (gc + j < N) dst[(c << 2) + j] = src[(c << 2) + j];
                    }
                }
            }
            __syncthreads();
        }
    }
}

// ---------------- BN reduce + finalize: partials -> pscale/pshift ----------------
__global__ __launch_bounds__(256) void bn_reduce(
    const float* __restrict__ partials, const float* __restrict__ gamma,
    const float* __restrict__ beta, float* __restrict__ pscale,
    float* __restrict__ pshift, float invM) {
    const int c = blockIdx.x;  // 0..HID-1
    const int t = threadIdx.x;
    float s1 = 0.f, s2 = 0.f;
    for (int i = t; i < MT_TILES * 2; i += 256) {
        const float* pw = partials + (size_t)i * 2 * 640;
        s1 += pw[c];
        s2 += pw[640 + c];
    }
    __shared__ float r1[256], r2[256];
    r1[t] = s1; r2[t] = s2;
    __syncthreads();
    for (int off = 128; off > 0; off >>= 1) {
        if (t < off) { r1[t] += r1[t + off]; r2[t] += r2[t + off]; }
        __syncthreads();
    }
    if (t == 0) {
        float mu = r1[0] * invM;
        float var = r2[0] * invM - mu * mu;
        float rs = rsqrtf(var + BN_EPS);
        float g = gamma[c] * rs;
        pscale[c] = g;
        pshift[c] = beta[c] - mu * g;
    }
}

extern "C" void kernel_launch(void* const* d_in, const int* in_sizes, int n_in,
                              void* d_out, int out_size, void* d_ws, size_t ws_size,
                              hipStream_t stream) {
    const float* x = (const float*)d_in[0];
    const int* ei = (const int*)d_in[1];
    const float* lin_in_w = (const float*)d_in[3];
    const float* lin_in_b = (const float*)d_in[4];
    const float* w1 = (const float*)d_in[5];
    const float* b1 = (const float*)d_in[6];
    const float* gamma = (const float*)d_in[7];
    const float* beta = (const float*)d_in[8];
    const float* w2 = (const float*)d_in[9];
    const float* b2 = (const float*)d_in[10];
    float* out = (float*)d_out;

    char* p = (char*)d_ws;
    auto alloc = [&](size_t bytes) {
        char* r = p;
        p += (bytes + 255) & ~(size_t)255;
        return r;
    };
    ushort_t* xb  = (ushort_t*)alloc((size_t)MPAD * K0P * 2);
    ushort_t* h   = (ushort_t*)alloc((size_t)MPAD * K1P * 2);
    ushort_t* agg = (ushort_t*)alloc((size_t)MPAD * K1P * 2);
    ushort_t* z   = (ushort_t*)alloc((size_t)MPAD * K2P * 2);
    ushort_t* lint = (ushort_t*)alloc((size_t)N0P * K0P * 2);
    ushort_t* w1t  = (ushort_t*)alloc((size_t)NLAYERS * N1P * K1P * 2);
    ushort_t* w2t  = (ushort_t*)alloc((size_t)NLAYERS * N0P * K2P * 2);
    int* deg    = (int*)alloc(NNODES * 4);
    int* cursor = (int*)alloc(NNODES * 4);
    int* offs   = (int*)alloc((NNODES + 1) * 4);
    int* bsum   = (int*)alloc(1024);
    int* csr    = (int*)alloc((size_t)NEDGES * 4);
    float* partials = (float*)alloc((size_t)MT_TILES * 2 * 2 * 640 * 4);  // 4.0 MB
    float* pscale = (float*)alloc(HID * 4);
    float* pshift = (float*)alloc(HID * 4);
    int* mode   = (int*)alloc(256);
    (void)ws_size; (void)in_sizes; (void)n_in; (void)out_size;

    hipMemsetAsync(deg, 0, NNODES * 4, stream);
    hipMemsetAsync(h + (size_t)NNODES * K1P, 0, (size_t)(MPAD - NNODES) * K1P * 2, stream);

    // CSR build
    detect_mode_kernel<<<1, 64, 0, stream>>>((const unsigned int*)ei, mode);
    hist_kernel<<<(NEDGES + 255) / 256, 256, 0, stream>>>(ei, mode, deg);
    const int nb = (NNODES + 255) / 256;
    scan_block_sums<<<nb, 256, 0, stream>>>(deg, bsum, NNODES);
    scan_bsums<<<1, 256, 0, stream>>>(bsum, nb);
    scan_final<<<nb, 256, 0, stream>>>(deg, bsum, offs, cursor, NNODES);
    fill_csr<<<(NEDGES + 255) / 256, 256, 0, stream>>>(ei, mode, cursor, csr);

    // conversions (LDS-tiled transposes; both global sides coalesced)
    cast_x_kernel<<<(NNODES * 32 + 255) / 256, 256, 0, stream>>>(x, xb);
    transpose_w<<<dim3(K0P / 32, N0P / 32, 1), 256, 0, stream>>>(
        lin_in_w, lint, IN_DIM, EMB, K0P, N0P);
    transpose_w<<<dim3(K1P / 32, N1P / 32, NLAYERS), 256, 0, stream>>>(
        w1, w1t, EMB, HID, K1P, N1P);
    transpose_w<<<dim3(K2P / 32, N0P / 32, NLAYERS), 256, 0, stream>>>(
        w2, w2t, HID, EMB, K2P, N0P);

    // XCD-colocated 1D grids: 8 * ceil(391/8) * NB
    const int G3 = 8 * 49 * 3;  // 1176
    const int G5 = 8 * 49 * 5;  // 1960

    // input linear: h = x @ lin_in_w + b  (bf16 out)
    gemm_mfma<0, 0, 0, 1><<<G3, 256, 0, stream>>>(
        xb, K0P, lint, K0P, lin_in_b, h, K1P, NNODES, EMB, K0P,
        nullptr, nullptr, 0, nullptr, 3);

    for (int l = 0; l < NLAYERS; ++l) {
        aggregate_bf16<<<(NNODES / 2 + 3) / 4, 256, 0, stream>>>(h, agg, offs, csr);
        // z = agg @ w1[l] + b1[l]  (bf16 out + race-free partial col stats)
        gemm_mfma<0, 0, 1, 1><<<G5, 256, 0, stream>>>(
            agg, K1P, w1t + (size_t)l * N1P * K1P, K1P, b1 + (size_t)l * HID,
            z, K2P, NNODES, HID, K1P,
            nullptr, nullptr, 0, partials, 5);
        bn_reduce<<<HID, 256, 0, stream>>>(
            partials, gamma + (size_t)l * HID, beta + (size_t)l * HID,
            pscale, pshift, 1.f / NNODES);
        // h_new = relu?( relu(BN(z)) @ w2[l] + b2[l] )  — BN+ReLU fused into A staging
        if (l < NLAYERS - 1) {
            gemm_mfma<1, 1, 0, 1><<<G3, 256, 0, stream>>>(
                z, K2P, w2t + (size_t)l * N0P * K2P, K2P, b2 + (size_t)l * EMB,
                h, K1P, NNODES, EMB, K2P,
                pscale, pshift, HID, nullptr, 3);
        } else {
            gemm_mfma<1, 0, 0, 0><<<G3, 256, 0, stream>>>(
                z, K2P, w2t + (size_t)l * N0P * K2P, K2P, b2 + (size_t)l * EMB,
                out, EMB, NNODES, EMB, K2P,
                pscale, pshift, HID, nullptr, 3);
        }
    }
}